// Round 2
// baseline (174.389 us; speedup 1.0000x reference)
//
#include <hip/hip_runtime.h>
#include <hip/hip_bf16.h>

#define GN 4096
#define GF 512
#define GH 8
#define GC 128
#define CAP 256          // max stored neighbors/row; deg ~ Bin(4096,0.01) = 41±6.4
#define LCAP 128         // attn LDS cap; P(deg>128) < 1e-20 for this graph
#define XS 72            // padded LDS row stride (u16): 144 B, 16B-aligned

typedef __hip_bfloat16 bf16;
typedef unsigned short u16;
typedef unsigned int u32;
typedef __attribute__((ext_vector_type(8))) short bf16x8;   // 8 bf16 = 4 VGPRs
typedef __attribute__((ext_vector_type(4))) float f32x4;

static __device__ inline u16 f2u16(float x) {
    union { bf16 b; u16 u; } cv;
    cv.b = __float2bfloat16(x);
    return cv.u;
}

static __device__ inline float bf2f(short s) {
    return __uint_as_float((u32)(u16)s << 16);
}

// ---------------------------------------------------------------------------
// Kernel 1 (fused prep + csr — r10-verified, unchanged): heterogeneous block
// ranges. [0,1024): X fp32->bf16. [1024,1088): W transpose to WT[h][n][k].
// [1088,5184): csr row compaction via wave ballot.
// ---------------------------------------------------------------------------
__global__ __launch_bounds__(256) void prep_csr_kernel(
    const float* __restrict__ A, const float* __restrict__ X,
    const float* __restrict__ W, int* __restrict__ deg,
    u16* __restrict__ lists, u16* __restrict__ Xb, u16* __restrict__ WT)
{
    __shared__ u16 sT[16][520];            // 16.6 KB; csr aliases sT[0..1] as cnt
    int tid = threadIdx.x;
    int b   = blockIdx.x;

    if (b < 1024) {
        size_t idx = ((size_t)b * 256 + tid) * 8;
        float4 v0 = *(const float4*)(X + idx);
        float4 v1 = *(const float4*)(X + idx + 4);
        u16 o[8] = {f2u16(v0.x), f2u16(v0.y), f2u16(v0.z), f2u16(v0.w),
                    f2u16(v1.x), f2u16(v1.y), f2u16(v1.z), f2u16(v1.w)};
        *(bf16x8*)(Xb + idx) = *(bf16x8*)o;
        return;
    }
    if (b < 1088) {
        int wb = b - 1024;                 // 0..63
        int h  = wb >> 3;
        int s16 = (wb & 7) * 16;
        const float* Wh = W + (size_t)h * GF * GC;
        for (int pass = 0; pass < 8; ++pass) {
            int k  = pass * 64 + (tid >> 2);
            int n4 = tid & 3;
            float4 v = *(const float4*)&Wh[(size_t)k * GC + s16 + n4 * 4];
            sT[n4 * 4 + 0][k] = f2u16(v.x);
            sT[n4 * 4 + 1][k] = f2u16(v.y);
            sT[n4 * 4 + 2][k] = f2u16(v.z);
            sT[n4 * 4 + 3][k] = f2u16(v.w);
        }
        __syncthreads();
        int n = tid >> 4, seg = tid & 15;
        u16* dst = WT + ((size_t)h * GC + s16 + n) * GF + seg * 32;
#pragma unroll
        for (int s = 0; s < 4; ++s)
            *(bf16x8*)(dst + s * 8) = *(const bf16x8*)&sT[n][seg * 32 + s * 8];
        return;
    }

    // ---- csr: row i ----
    int i    = b - 1088;
    int lane = tid & 63;
    int* cnt = (int*)&sT[0][0];
    if (tid == 0) *cnt = 0;
    __syncthreads();

    u16* row = lists + (size_t)i * CAP;
    const float4* Arow = (const float4*)(A + (size_t)i * GN);
    unsigned long long ltmask = (lane == 63) ? ~0ull >> 1
                                             : (1ull << lane) - 1;
#pragma unroll
    for (int it = 0; it < 4; ++it) {
        int qd = it * 256 + tid;
        float4 a = Arow[qd];
        int j = qd * 4;
#pragma unroll
        for (int comp = 0; comp < 4; ++comp) {
            float av = comp == 0 ? a.x : comp == 1 ? a.y : comp == 2 ? a.z : a.w;
            bool flag = av > 0.5f;
            unsigned long long m = __ballot(flag);
            if (m) {
                int base = 0;
                if (lane == 0) base = atomicAdd(cnt, __popcll(m));
                base = __shfl(base, 0);
                if (flag) {
                    int s = base + __popcll(m & ltmask);
                    if (s < CAP) row[s] = (u16)(j + comp);
                }
            }
        }
    }
    __syncthreads();
    if (tid == 0) deg[i] = *cnt < CAP ? *cnt : CAP;
}

// ---------------------------------------------------------------------------
// Kernel 2 (MFMA feats): feats = Xb @ WT^T. BM=64 BN=128 BK=64 -> 512 blocks.
// NEW (r1): featsb stored [N][H][C] (2 KB contiguous per node) so the attn
// gather reads one contiguous 2 KB chunk per neighbor. Each (n,h) chunk is
// a 256 B aligned block written by exactly one workgroup -> full-line writes,
// no cross-XCD partial-line sharing. s_self/s_neigh stored transposed [N][H].
// ---------------------------------------------------------------------------
__global__ __launch_bounds__(256) void feats_kernel(
    const u16* __restrict__ Xb, const u16* __restrict__ WT,
    const float* __restrict__ a_self, const float* __restrict__ a_neigh,
    bf16* __restrict__ featsb, float* __restrict__ ssT,
    float* __restrict__ snT)
{
    __shared__ u16 sX[64 * XS];    //  9.2 KB
    __shared__ u16 sW[128 * XS];   // 18.4 KB

    int h   = blockIdx.x >> 6;
    int n0  = (blockIdx.x & 63) << 6;
    int tid = threadIdx.x;
    int lane = tid & 63, wv = tid >> 6;
    int lm = lane & 15, q = lane >> 4;

    const u16* Xp = Xb + (size_t)n0 * GF;
    const u16* Wp = WT + (size_t)h * GC * GF;

    uint4 xr[2], wr[4];

#define ISSUE_TILE(K0)                                                        \
    {                                                                         \
        _Pragma("unroll")                                                     \
        for (int it = 0; it < 2; ++it) {                                      \
            int idx = it * 256 + tid, row = idx >> 3, c = idx & 7;            \
            xr[it] = *(const uint4*)&Xp[(size_t)row * GF + (K0) + c * 8];     \
        }                                                                     \
        _Pragma("unroll")                                                     \
        for (int it = 0; it < 4; ++it) {                                      \
            int idx = it * 256 + tid, row = idx >> 3, c = idx & 7;            \
            wr[it] = *(const uint4*)&Wp[(size_t)row * GF + (K0) + c * 8];     \
        }                                                                     \
    }

#define STORE_TILE()                                                          \
    {                                                                         \
        _Pragma("unroll")                                                     \
        for (int it = 0; it < 2; ++it) {                                      \
            int idx = it * 256 + tid, row = idx >> 3, c = idx & 7;            \
            *(uint4*)&sX[row * XS + c * 8] = xr[it];                          \
        }                                                                     \
        _Pragma("unroll")                                                     \
        for (int it = 0; it < 4; ++it) {                                      \
            int idx = it * 256 + tid, row = idx >> 3, c = idx & 7;            \
            *(uint4*)&sW[row * XS + c * 8] = wr[it];                          \
        }                                                                     \
    }

    f32x4 acc[8];
#pragma unroll
    for (int nt = 0; nt < 8; ++nt) acc[nt] = (f32x4){0.f, 0.f, 0.f, 0.f};

    ISSUE_TILE(0)
    STORE_TILE()

    for (int k0 = 0; k0 < GF; k0 += 64) {
        __syncthreads();                       // tile k0 visible
        if (k0 + 64 < GF) ISSUE_TILE(k0 + 64)  // next tile in flight

#pragma unroll
        for (int ks = 0; ks < 64; ks += 32) {
            bf16x8 af = *(const bf16x8*)&sX[(wv * 16 + lm) * XS + ks + q * 8];
            bf16x8 bfr[8];
#pragma unroll
            for (int nt = 0; nt < 8; ++nt)
                bfr[nt] = *(const bf16x8*)&sW[(nt * 16 + lm) * XS + ks + q * 8];
#pragma unroll
            for (int nt = 0; nt < 8; ++nt)
                acc[nt] = __builtin_amdgcn_mfma_f32_16x16x32_bf16(
                    af, bfr[nt], acc[nt], 0, 0, 0);
        }
        __syncthreads();                       // readers done
        if (k0 + 64 < GF) STORE_TILE()
    }
#undef ISSUE_TILE
#undef STORE_TILE

    // epilogue: bf16 feats store ([N][H][C]) + fused transposed score vectors
    float aS[8], aN[8];
#pragma unroll
    for (int nt = 0; nt < 8; ++nt) {
        aS[nt] = a_self[h * GC + nt * 16 + lm];
        aN[nt] = a_neigh[h * GC + nt * 16 + lm];
    }
    float vs[4] = {0.f, 0.f, 0.f, 0.f};
    float vn[4] = {0.f, 0.f, 0.f, 0.f};
    int rbase = n0 + wv * 16 + q * 4;          // D row = quad*4+reg (m89)
#pragma unroll
    for (int nt = 0; nt < 8; ++nt) {
        f32x4 v = acc[nt];
        int col = nt * 16 + lm;                // D col = lane&15
#pragma unroll
        for (int r = 0; r < 4; ++r) {
            featsb[((size_t)(rbase + r) * GH + h) * GC + col] = __float2bfloat16(v[r]);
            vs[r] += v[r] * aS[nt];
            vn[r] += v[r] * aN[nt];
        }
    }
#pragma unroll
    for (int r = 0; r < 4; ++r) {
        for (int off = 1; off < 16; off <<= 1) {
            vs[r] += __shfl_xor(vs[r], off);
            vn[r] += __shfl_xor(vn[r], off);
        }
        if (lm == 0) {
            ssT[(rbase + r) * GH + h] = vs[r];
            snT[(rbase + r) * GH + h] = vn[r];
        }
    }
}

// ---------------------------------------------------------------------------
// Kernel 3 (attn — r1 restructure): ONE WAVE per node i, ALL 8 HEADS.
// 4096 waves -> 1024 blocks. featsb is [N][H][C]: a neighbor's full 8-head
// feature row = contiguous 2 KB = 64 lanes x 32 B -> 2 dwordx4 loads per
// neighbor (vs 8 narrow dword loads before; 4x fewer vmem instructions at
// identical bytes). Lane l owns head l>>3, channels (l&7)*16..+16.
// Scores for all 8 heads computed per-lane from transposed [N][H] vectors;
// softmax per head via shuffle reduce; P in LDS [k][8] (broadcast reads).
// Zero barriers (single-wave LDS coherence via lgkmcnt).
// ---------------------------------------------------------------------------
__global__ __launch_bounds__(256) void attn_kernel(
    const int* __restrict__ deg, const u16* __restrict__ lists,
    const float* __restrict__ bias, const bf16* __restrict__ featsb,
    const float* __restrict__ ssT, const float* __restrict__ snT,
    float* __restrict__ out)
{
    int tid  = threadIdx.x;
    int wv   = tid >> 6, lane = tid & 63;
    int i    = blockIdx.x * 4 + wv;        // 0..4095

    __shared__ float pbuf[4][LCAP * 8];    // 16 KB: exp'd scores [k][h]
    __shared__ u16  jbuf[4][LCAP];         //  1 KB: neighbor ids
    float* p  = pbuf[wv];
    u16*   jl = jbuf[wv];

    int M = deg[i];
    M = M < LCAP ? M : LCAP;
    const u16* row = lists + (size_t)i * CAP;

    float4 sa = *(const float4*)&ssT[(size_t)i * 8];
    float4 sb = *(const float4*)&ssT[(size_t)i * 8 + 4];
    float ssi[8] = {sa.x, sa.y, sa.z, sa.w, sb.x, sb.y, sb.z, sb.w};

    float mx[8], sm[8];
#pragma unroll
    for (int hh = 0; hh < 8; ++hh) { mx[hh] = -1e30f; sm[hh] = 0.f; }

    // pass 1: leaky scores for all 8 heads -> LDS; lane-local per-head max
    for (int k = lane; k < M; k += 64) {
        int j = row[k];
        jl[k] = (u16)j;
        float4 na = *(const float4*)&snT[(size_t)j * 8];
        float4 nb = *(const float4*)&snT[(size_t)j * 8 + 4];
        float sn[8] = {na.x, na.y, na.z, na.w, nb.x, nb.y, nb.z, nb.w};
#pragma unroll
        for (int hh = 0; hh < 8; ++hh) {
            float e = ssi[hh] + sn[hh];
            e = e > 0.f ? e : 0.2f * e;
            p[k * 8 + hh] = e;
            mx[hh] = fmaxf(mx[hh], e);
        }
    }
#pragma unroll
    for (int off = 32; off > 0; off >>= 1)
#pragma unroll
        for (int hh = 0; hh < 8; ++hh)
            mx[hh] = fmaxf(mx[hh], __shfl_xor(mx[hh], off));

    // pass 2: exp in place + per-head sums
    for (int k = lane; k < M; k += 64) {
#pragma unroll
        for (int hh = 0; hh < 8; ++hh) {
            float e = __expf(p[k * 8 + hh] - mx[hh]);
            p[k * 8 + hh] = e;
            sm[hh] += e;
        }
    }
#pragma unroll
    for (int off = 32; off > 0; off >>= 1)
#pragma unroll
        for (int hh = 0; hh < 8; ++hh)
            sm[hh] += __shfl_xor(sm[hh], off);

    int h = lane >> 3;                     // this lane's head
    float denom = sm[0];
#pragma unroll
    for (int hh = 1; hh < 8; ++hh) denom = (h == hh) ? sm[hh] : denom;
    float inv = 1.f / denom;

    // gather: lane reads 32 B (16 bf16 channels) of each neighbor's 2 KB row
    const u16* fb = (const u16*)featsb + (size_t)lane * 16;
    float acc[16];
#pragma unroll
    for (int c = 0; c < 16; ++c) acc[c] = 0.f;

    int k = 0;
    for (; k + 4 <= M; k += 4) {
        int j0 = jl[k], j1 = jl[k + 1], j2 = jl[k + 2], j3 = jl[k + 3];
        float p0 = p[k * 8 + h],       p1 = p[(k + 1) * 8 + h];
        float p2 = p[(k + 2) * 8 + h], p3 = p[(k + 3) * 8 + h];
        bf16x8 q0a = *(const bf16x8*)(fb + (size_t)j0 * 1024);
        bf16x8 q0b = *(const bf16x8*)(fb + (size_t)j0 * 1024 + 8);
        bf16x8 q1a = *(const bf16x8*)(fb + (size_t)j1 * 1024);
        bf16x8 q1b = *(const bf16x8*)(fb + (size_t)j1 * 1024 + 8);
        bf16x8 q2a = *(const bf16x8*)(fb + (size_t)j2 * 1024);
        bf16x8 q2b = *(const bf16x8*)(fb + (size_t)j2 * 1024 + 8);
        bf16x8 q3a = *(const bf16x8*)(fb + (size_t)j3 * 1024);
        bf16x8 q3b = *(const bf16x8*)(fb + (size_t)j3 * 1024 + 8);
#pragma unroll
        for (int c = 0; c < 8; ++c) {
            acc[c]     += p0 * bf2f(q0a[c]);
            acc[c + 8] += p0 * bf2f(q0b[c]);
            acc[c]     += p1 * bf2f(q1a[c]);
            acc[c + 8] += p1 * bf2f(q1b[c]);
            acc[c]     += p2 * bf2f(q2a[c]);
            acc[c + 8] += p2 * bf2f(q2b[c]);
            acc[c]     += p3 * bf2f(q3a[c]);
            acc[c + 8] += p3 * bf2f(q3b[c]);
        }
    }
    for (; k < M; ++k) {
        int j0 = jl[k];
        float p0 = p[k * 8 + h];
        bf16x8 q0a = *(const bf16x8*)(fb + (size_t)j0 * 1024);
        bf16x8 q0b = *(const bf16x8*)(fb + (size_t)j0 * 1024 + 8);
#pragma unroll
        for (int c = 0; c < 8; ++c) {
            acc[c]     += p0 * bf2f(q0a[c]);
            acc[c + 8] += p0 * bf2f(q0b[c]);
        }
    }

    // epilogue: scale, bias, relu, store 64 B contiguous per lane
    const float* bp = bias + lane * 16;    // == h*GC + (lane&7)*16 since GC=128
    float* op = out + (size_t)i * (GH * GC) + lane * 16;
#pragma unroll
    for (int c4 = 0; c4 < 4; ++c4) {
        float4 bv = *(const float4*)(bp + c4 * 4);
        float4 o;
        o.x = fmaxf(acc[c4 * 4 + 0] * inv + bv.x, 0.f);
        o.y = fmaxf(acc[c4 * 4 + 1] * inv + bv.y, 0.f);
        o.z = fmaxf(acc[c4 * 4 + 2] * inv + bv.z, 0.f);
        o.w = fmaxf(acc[c4 * 4 + 3] * inv + bv.w, 0.f);
        *(float4*)(op + c4 * 4) = o;
    }
}

// ---------------------------------------------------------------------------
extern "C" void kernel_launch(void* const* d_in, const int* in_sizes, int n_in,
                              void* d_out, int out_size, void* d_ws, size_t ws_size,
                              hipStream_t stream)
{
    const float* X       = (const float*)d_in[0];
    const float* A       = (const float*)d_in[1];
    const float* W       = (const float*)d_in[2];
    const float* a_self  = (const float*)d_in[3];
    const float* a_neigh = (const float*)d_in[4];
    const float* bias    = (const float*)d_in[5];
    float* out = (float*)d_out;

    // ws layout: featsb bf16 [N*H*C] | ssT f32 [N*H] | snT f32 [N*H]
    //            | deg i32 [N] | lists u16 [N*CAP] | Xb u16 [N*F] | WT u16 [H*C*F]
    bf16*  featsb = (bf16*)d_ws;
    float* ssT    = (float*)(featsb + (size_t)GH * GN * GC);
    float* snT    = ssT + (size_t)GH * GN;
    int*   deg    = (int*)(snT + (size_t)GH * GN);
    u16*   lists  = (u16*)(deg + GN);
    u16*   Xb     = lists + (size_t)GN * CAP;
    u16*   WT     = Xb + (size_t)GN * GF;

    prep_csr_kernel<<<1088 + GN, 256, 0, stream>>>(A, X, W, deg, lists, Xb, WT);
    feats_kernel<<<GH * 64, 256, 0, stream>>>(Xb, WT, a_self, a_neigh,
                                              featsb, ssT, snT);
    attn_kernel<<<GN / 4, 256, 0, stream>>>(deg, lists, bias, featsb,
                                            ssT, snT, out);
}